// Round 1
// baseline (435.429 us; speedup 1.0000x reference)
//
#include <hip/hip_runtime.h>
#include <hip/hip_bf16.h>
#include <math.h>

typedef float f32x4 __attribute__((ext_vector_type(4)));
typedef __bf16 bf16x8 __attribute__((ext_vector_type(8)));
typedef unsigned short ushort8 __attribute__((ext_vector_type(8)));

#define BSZ 8192
#define DIM 2048
#define NTILE 64          // 8192 / 128 tiles per side
#define KSTEPS 32         // 2048 / 64

// ---------- round-to-nearest-even fp32 -> bf16 ----------
__device__ __forceinline__ unsigned short f2bf(float f) {
  union { float f; unsigned int u; } c; c.f = f;
  unsigned int r = c.u + 0x7FFFu + ((c.u >> 16) & 1u);
  return (unsigned short)(r >> 16);
}

// ---------- kernel 1: row-normalize fp32 -> bf16 ----------
__global__ void __launch_bounds__(256) k_norm(const float* __restrict__ in,
                                              unsigned short* __restrict__ out) {
  const int row = blockIdx.x;
  const int tid = threadIdx.x;
  const float4* rp = (const float4*)(in + (size_t)row * DIM);
  float4 v0 = rp[tid * 2];
  float4 v1 = rp[tid * 2 + 1];
  float ss = v0.x * v0.x + v0.y * v0.y + v0.z * v0.z + v0.w * v0.w
           + v1.x * v1.x + v1.y * v1.y + v1.z * v1.z + v1.w * v1.w;
#pragma unroll
  for (int m = 32; m >= 1; m >>= 1) ss += __shfl_xor(ss, m);
  __shared__ float sred[4];
  if ((tid & 63) == 0) sred[tid >> 6] = ss;
  __syncthreads();
  float tot = sred[0] + sred[1] + sred[2] + sred[3];
  float inv = 1.0f / fmaxf(sqrtf(tot), 1e-8f);
  float v[8] = {v0.x, v0.y, v0.z, v0.w, v1.x, v1.y, v1.z, v1.w};
  ushort8 o;
#pragma unroll
  for (int i = 0; i < 8; ++i) o[i] = f2bf(v[i] * inv);
  *(ushort8*)(out + (size_t)row * DIM + tid * 8) = o;
}

// ---------- kernel 2: fp32 diagonal cos(X_k, Y_k) ----------
__global__ void __launch_bounds__(256) k_diag(const float* __restrict__ X,
                                              const float* __restrict__ Y,
                                              float* __restrict__ dg) {
  const int row = blockIdx.x;
  const int tid = threadIdx.x;
  const float4* xp = (const float4*)(X + (size_t)row * DIM);
  const float4* yp = (const float4*)(Y + (size_t)row * DIM);
  float sxx = 0.f, syy = 0.f, sxy = 0.f;
#pragma unroll
  for (int i = 0; i < 2; ++i) {
    float4 x = xp[tid * 2 + i];
    float4 y = yp[tid * 2 + i];
    sxx += x.x * x.x + x.y * x.y + x.z * x.z + x.w * x.w;
    syy += y.x * y.x + y.y * y.y + y.z * y.z + y.w * y.w;
    sxy += x.x * y.x + x.y * y.y + x.z * y.z + x.w * y.w;
  }
#pragma unroll
  for (int m = 32; m >= 1; m >>= 1) {
    sxx += __shfl_xor(sxx, m);
    syy += __shfl_xor(syy, m);
    sxy += __shfl_xor(sxy, m);
  }
  __shared__ float sh[3][4];
  if ((tid & 63) == 0) {
    sh[0][tid >> 6] = sxx; sh[1][tid >> 6] = syy; sh[2][tid >> 6] = sxy;
  }
  __syncthreads();
  if (tid == 0) {
    float xx = sh[0][0] + sh[0][1] + sh[0][2] + sh[0][3];
    float yy = sh[1][0] + sh[1][1] + sh[1][2] + sh[1][3];
    float xy = sh[2][0] + sh[2][1] + sh[2][2] + sh[2][3];
    dg[row] = xy / (fmaxf(sqrtf(xx), 1e-8f) * fmaxf(sqrtf(yy), 1e-8f));
  }
}

// ---------- kernel 3: 128x128-tile bf16 MFMA GEMM, fused exp + row/col partial sums ----------
// S[i,j] = sum_k Xn[i,k]*Yn[j,k]  (B^T GEMM; both operands row-major along K)
// rowpart[bn][i] = sum over this tile's 128 cols of exp(S)   (unique slot per block)
// colpart[bm][j] = sum over this tile's 128 rows of exp(S)
__global__ void __launch_bounds__(256) k_gemm(const unsigned short* __restrict__ Xn,
                                              const unsigned short* __restrict__ Yn,
                                              float* __restrict__ rowpart,
                                              float* __restrict__ colpart) {
  const int bm = blockIdx.x & (NTILE - 1);
  const int bn = blockIdx.x >> 6;
  const int tileRow = bm * 128;
  const int tileCol = bn * 128;

  __shared__ __align__(16) unsigned short As[128][64];
  __shared__ __align__(16) unsigned short Bs[128][64];
  __shared__ float rsum2[2][128];
  __shared__ float csum2[2][128];

  const int tid = threadIdx.x;
  const int lane = tid & 63;
  const int w = tid >> 6;        // wave 0..3
  const int wr = w >> 1;         // wave row 0..1  (64-row sub-tile)
  const int wc = w & 1;          // wave col 0..1  (64-col sub-tile)
  const int lo = lane & 15;
  const int hi = lane >> 4;

  f32x4 acc[4][4];
#pragma unroll
  for (int m = 0; m < 4; ++m)
#pragma unroll
    for (int n = 0; n < 4; ++n) acc[m][n] = (f32x4){0.f, 0.f, 0.f, 0.f};

  // staging map: thread t covers row r4*32 + (t>>3), cols (t&7)*8 .. +8
  const int srow = tid >> 3;
  const int scol = (tid & 7) * 8;

  for (int t = 0; t < KSTEPS; ++t) {
    const int kbase = t * 64;
#pragma unroll
    for (int r4 = 0; r4 < 4; ++r4) {
      const int row = r4 * 32 + srow;
      *(ushort8*)&As[row][scol] =
          *(const ushort8*)&Xn[(size_t)(tileRow + row) * DIM + kbase + scol];
      *(ushort8*)&Bs[row][scol] =
          *(const ushort8*)&Yn[(size_t)(tileCol + row) * DIM + kbase + scol];
    }
    __syncthreads();

#pragma unroll
    for (int s = 0; s < 2; ++s) {
      bf16x8 a[4], b[4];
#pragma unroll
      for (int m = 0; m < 4; ++m)
        a[m] = *(const bf16x8*)&As[wr * 64 + m * 16 + lo][s * 32 + hi * 8];
#pragma unroll
      for (int n = 0; n < 4; ++n)
        b[n] = *(const bf16x8*)&Bs[wc * 64 + n * 16 + lo][s * 32 + hi * 8];
#pragma unroll
      for (int m = 0; m < 4; ++m)
#pragma unroll
        for (int n = 0; n < 4; ++n)
          acc[m][n] = __builtin_amdgcn_mfma_f32_16x16x32_bf16(a[m], b[n], acc[m][n], 0, 0, 0);
    }
    __syncthreads();
  }

  // ---- epilogue: exp + per-tile row/col sums ----
  // D layout (16x16x32): value at local (row = m*16 + hi*4 + q, col = n*16 + lo)
  float rp[4][4];   // [m][q]: per-lane sum over n (then reduce over lo)
  float cp[4];      // [n]   : per-lane sum over m,q (then reduce over hi)
#pragma unroll
  for (int m = 0; m < 4; ++m)
#pragma unroll
    for (int q = 0; q < 4; ++q) rp[m][q] = 0.f;
#pragma unroll
  for (int n = 0; n < 4; ++n) cp[n] = 0.f;

#pragma unroll
  for (int m = 0; m < 4; ++m)
#pragma unroll
    for (int n = 0; n < 4; ++n)
#pragma unroll
      for (int q = 0; q < 4; ++q) {
        float e = __expf(acc[m][n][q]);
        rp[m][q] += e;
        cp[n] += e;
      }

#pragma unroll
  for (int m = 0; m < 4; ++m)
#pragma unroll
    for (int q = 0; q < 4; ++q) {
      float v = rp[m][q];
      v += __shfl_xor(v, 1);
      v += __shfl_xor(v, 2);
      v += __shfl_xor(v, 4);
      v += __shfl_xor(v, 8);
      rp[m][q] = v;
    }
#pragma unroll
  for (int n = 0; n < 4; ++n) {
    float v = cp[n];
    v += __shfl_xor(v, 16);
    v += __shfl_xor(v, 32);
    cp[n] = v;
  }

  if (lo == 0) {
#pragma unroll
    for (int m = 0; m < 4; ++m)
#pragma unroll
      for (int q = 0; q < 4; ++q)
        rsum2[wc][wr * 64 + m * 16 + hi * 4 + q] = rp[m][q];
  }
  if (hi == 0) {
#pragma unroll
    for (int n = 0; n < 4; ++n)
      csum2[wr][wc * 64 + n * 16 + lo] = cp[n];
  }
  __syncthreads();

  if (tid < 128) {
    rowpart[(size_t)bn * BSZ + tileRow + tid] = rsum2[0][tid] + rsum2[1][tid];
    colpart[(size_t)bm * BSZ + tileCol + tid] = csum2[0][tid] + csum2[1][tid];
  }
}

// ---------- kernel 4: reduce partials + final expression ----------
__global__ void __launch_bounds__(256) k_final(const float* __restrict__ rowpart,
                                               const float* __restrict__ colpart,
                                               const float* __restrict__ dg,
                                               float* __restrict__ out) {
  const int k = blockIdx.x * 256 + threadIdx.x;
  float rs = 0.f, cs = 0.f;
#pragma unroll 8
  for (int s = 0; s < NTILE; ++s) {
    rs += rowpart[(size_t)s * BSZ + k];
    cs += colpart[(size_t)s * BSZ + k];
  }
  float d = dg[k];
  float p = __expf(d);
  out[k] = logf(cs - p) + logf(rs - p) - 2.0f * d;
}

extern "C" void kernel_launch(void* const* d_in, const int* in_sizes, int n_in,
                              void* d_out, int out_size, void* d_ws, size_t ws_size,
                              hipStream_t stream) {
  const float* X = (const float*)d_in[0];
  const float* Y = (const float*)d_in[1];
  float* out = (float*)d_out;

  char* ws = (char*)d_ws;
  // layout: Xn (32MB) | Yn (32MB) | diag (32KB) | rowpart (2MB) | colpart (2MB)
  unsigned short* Xn = (unsigned short*)ws;
  unsigned short* Yn = (unsigned short*)(ws + (size_t)BSZ * DIM * 2);
  float* diag = (float*)(ws + (size_t)BSZ * DIM * 4);
  float* rowpart = (float*)(ws + (size_t)BSZ * DIM * 4 + BSZ * 4);
  float* colpart = (float*)(ws + (size_t)BSZ * DIM * 4 + BSZ * 4 + (size_t)NTILE * BSZ * 4);

  k_norm<<<BSZ, 256, 0, stream>>>(X, Xn);
  k_norm<<<BSZ, 256, 0, stream>>>(Y, Yn);
  k_diag<<<BSZ, 256, 0, stream>>>(X, Y, diag);
  k_gemm<<<NTILE * NTILE, 256, 0, stream>>>(Xn, Yn, rowpart, colpart);
  k_final<<<BSZ / 256, 256, 0, stream>>>(rowpart, colpart, diag, out);
}

// Round 2
// 351.578 us; speedup vs baseline: 1.2385x; 1.2385x over previous
//
#include <hip/hip_runtime.h>
#include <hip/hip_bf16.h>
#include <math.h>

typedef float f32x4 __attribute__((ext_vector_type(4)));
typedef __bf16 bf16x8 __attribute__((ext_vector_type(8)));
typedef unsigned short ushort8 __attribute__((ext_vector_type(8)));

#define BSZ 8192
#define DIM 2048
#define NTILE 64          // 8192 / 128 tiles per side
#define KSTEPS 32         // 2048 / 64

// ---------- round-to-nearest-even fp32 -> bf16 ----------
__device__ __forceinline__ unsigned short f2bf(float f) {
  union { float f; unsigned int u; } c; c.f = f;
  unsigned int r = c.u + 0x7FFFu + ((c.u >> 16) & 1u);
  return (unsigned short)(r >> 16);
}

// ---------- kernel 1: row-normalize fp32 -> bf16 ----------
__global__ void __launch_bounds__(256) k_norm(const float* __restrict__ in,
                                              unsigned short* __restrict__ out) {
  const int row = blockIdx.x;
  const int tid = threadIdx.x;
  const float4* rp = (const float4*)(in + (size_t)row * DIM);
  float4 v0 = rp[tid * 2];
  float4 v1 = rp[tid * 2 + 1];
  float ss = v0.x * v0.x + v0.y * v0.y + v0.z * v0.z + v0.w * v0.w
           + v1.x * v1.x + v1.y * v1.y + v1.z * v1.z + v1.w * v1.w;
#pragma unroll
  for (int m = 32; m >= 1; m >>= 1) ss += __shfl_xor(ss, m);
  __shared__ float sred[4];
  if ((tid & 63) == 0) sred[tid >> 6] = ss;
  __syncthreads();
  float tot = sred[0] + sred[1] + sred[2] + sred[3];
  float inv = 1.0f / fmaxf(sqrtf(tot), 1e-8f);
  float v[8] = {v0.x, v0.y, v0.z, v0.w, v1.x, v1.y, v1.z, v1.w};
  ushort8 o;
#pragma unroll
  for (int i = 0; i < 8; ++i) o[i] = f2bf(v[i] * inv);
  *(ushort8*)(out + (size_t)row * DIM + tid * 8) = o;
}

// ---------- kernel 2: fp32 diagonal cos(X_k, Y_k) ----------
__global__ void __launch_bounds__(256) k_diag(const float* __restrict__ X,
                                              const float* __restrict__ Y,
                                              float* __restrict__ dg) {
  const int row = blockIdx.x;
  const int tid = threadIdx.x;
  const float4* xp = (const float4*)(X + (size_t)row * DIM);
  const float4* yp = (const float4*)(Y + (size_t)row * DIM);
  float sxx = 0.f, syy = 0.f, sxy = 0.f;
#pragma unroll
  for (int i = 0; i < 2; ++i) {
    float4 x = xp[tid * 2 + i];
    float4 y = yp[tid * 2 + i];
    sxx += x.x * x.x + x.y * x.y + x.z * x.z + x.w * x.w;
    syy += y.x * y.x + y.y * y.y + y.z * y.z + y.w * y.w;
    sxy += x.x * y.x + x.y * y.y + x.z * y.z + x.w * y.w;
  }
#pragma unroll
  for (int m = 32; m >= 1; m >>= 1) {
    sxx += __shfl_xor(sxx, m);
    syy += __shfl_xor(syy, m);
    sxy += __shfl_xor(sxy, m);
  }
  __shared__ float sh[3][4];
  if ((tid & 63) == 0) {
    sh[0][tid >> 6] = sxx; sh[1][tid >> 6] = syy; sh[2][tid >> 6] = sxy;
  }
  __syncthreads();
  if (tid == 0) {
    float xx = sh[0][0] + sh[0][1] + sh[0][2] + sh[0][3];
    float yy = sh[1][0] + sh[1][1] + sh[1][2] + sh[1][3];
    float xy = sh[2][0] + sh[2][1] + sh[2][2] + sh[2][3];
    dg[row] = xy / (fmaxf(sqrtf(xx), 1e-8f) * fmaxf(sqrtf(yy), 1e-8f));
  }
}

// ---------- kernel 3: 128x128-tile bf16 MFMA GEMM ----------
// Staging via global_load_lds width-16 (linear LDS dest = wave-uniform base +
// lane*16). Bank-conflict fix per rule #21: XOR-swizzle applied as inverse
// permutation on the GLOBAL source address + same XOR on the ds_read side.
//   physical 16B-chunk p of LDS row r holds logical chunk p ^ (r&7)
//   write: lane l (row r&7 = l>>3, phys chunk l&7) sources logical chunk (l&7)^(l>>3)
//   read : logical chunk c of row r -> physical chunk c ^ (r&7),  r&7 = lo&7
__global__ void __launch_bounds__(256) k_gemm(const unsigned short* __restrict__ Xn,
                                              const unsigned short* __restrict__ Yn,
                                              float* __restrict__ rowpart,
                                              float* __restrict__ colpart) {
  const int bm = blockIdx.x & (NTILE - 1);
  const int bn = blockIdx.x >> 6;
  const int tileRow = bm * 128;
  const int tileCol = bn * 128;

  __shared__ __align__(16) unsigned short As[128][64];
  __shared__ __align__(16) unsigned short Bs[128][64];
  __shared__ float rsum2[2][128];
  __shared__ float csum2[2][128];

  const int tid = threadIdx.x;
  const int lane = tid & 63;
  const int w = tid >> 6;        // wave 0..3
  const int wr = w >> 1;         // wave row 0..1  (64-row sub-tile)
  const int wc = w & 1;          // wave col 0..1  (64-col sub-tile)
  const int lo = lane & 15;
  const int hi = lane >> 4;

  f32x4 acc[4][4];
#pragma unroll
  for (int m = 0; m < 4; ++m)
#pragma unroll
    for (int n = 0; n < 4; ++n) acc[m][n] = (f32x4){0.f, 0.f, 0.f, 0.f};

  // ---- per-lane global source for global_load_lds staging ----
  // wave w stages rows [w*32, w*32+32) of each tile, 8 rows per issue, 4 issues.
  // lane l: row offset l>>3, swizzled source chunk (l&7)^(l>>3).
  const size_t lrow = (size_t)(lane >> 3);
  const int    lcol = (((lane & 7) ^ (lane >> 3)) * 8);
  const unsigned short* gxa = Xn + ((size_t)(tileRow + w * 32) + lrow) * DIM + lcol;
  const unsigned short* gyb = Yn + ((size_t)(tileCol + w * 32) + lrow) * DIM + lcol;

  for (int t = 0; t < KSTEPS; ++t) {
    const int kbase = t * 64;
#pragma unroll
    for (int i = 0; i < 4; ++i) {
      __builtin_amdgcn_global_load_lds(
          (const __attribute__((address_space(1))) void*)(gxa + (size_t)i * 8 * DIM + kbase),
          (__attribute__((address_space(3))) void*)&As[w * 32 + i * 8][0],
          16, 0, 0);
      __builtin_amdgcn_global_load_lds(
          (const __attribute__((address_space(1))) void*)(gyb + (size_t)i * 8 * DIM + kbase),
          (__attribute__((address_space(3))) void*)&Bs[w * 32 + i * 8][0],
          16, 0, 0);
    }
    __syncthreads();   // compiler inserts s_waitcnt vmcnt(0) before s_barrier

#pragma unroll
    for (int s = 0; s < 2; ++s) {
      bf16x8 a[4], b[4];
#pragma unroll
      for (int m = 0; m < 4; ++m)
        a[m] = *(const bf16x8*)&As[wr * 64 + m * 16 + lo][((s * 4 + hi) ^ (lo & 7)) * 8];
#pragma unroll
      for (int n = 0; n < 4; ++n)
        b[n] = *(const bf16x8*)&Bs[wc * 64 + n * 16 + lo][((s * 4 + hi) ^ (lo & 7)) * 8];
#pragma unroll
      for (int m = 0; m < 4; ++m)
#pragma unroll
        for (int n = 0; n < 4; ++n)
          acc[m][n] = __builtin_amdgcn_mfma_f32_16x16x32_bf16(a[m], b[n], acc[m][n], 0, 0, 0);
    }
    __syncthreads();
  }

  // ---- epilogue: exp + per-tile row/col sums ----
  // D layout (16x16x32): value at local (row = m*16 + hi*4 + q, col = n*16 + lo)
  float rp[4][4];   // [m][q]: per-lane sum over n (then reduce over lo)
  float cp[4];      // [n]   : per-lane sum over m,q (then reduce over hi)
#pragma unroll
  for (int m = 0; m < 4; ++m)
#pragma unroll
    for (int q = 0; q < 4; ++q) rp[m][q] = 0.f;
#pragma unroll
  for (int n = 0; n < 4; ++n) cp[n] = 0.f;

#pragma unroll
  for (int m = 0; m < 4; ++m)
#pragma unroll
    for (int n = 0; n < 4; ++n)
#pragma unroll
      for (int q = 0; q < 4; ++q) {
        float e = __expf(acc[m][n][q]);
        rp[m][q] += e;
        cp[n] += e;
      }

#pragma unroll
  for (int m = 0; m < 4; ++m)
#pragma unroll
    for (int q = 0; q < 4; ++q) {
      float v = rp[m][q];
      v += __shfl_xor(v, 1);
      v += __shfl_xor(v, 2);
      v += __shfl_xor(v, 4);
      v += __shfl_xor(v, 8);
      rp[m][q] = v;
    }
#pragma unroll
  for (int n = 0; n < 4; ++n) {
    float v = cp[n];
    v += __shfl_xor(v, 16);
    v += __shfl_xor(v, 32);
    cp[n] = v;
  }

  if (lo == 0) {
#pragma unroll
    for (int m = 0; m < 4; ++m)
#pragma unroll
      for (int q = 0; q < 4; ++q)
        rsum2[wc][wr * 64 + m * 16 + hi * 4 + q] = rp[m][q];
  }
  if (hi == 0) {
#pragma unroll
    for (int n = 0; n < 4; ++n)
      csum2[wr][wc * 64 + n * 16 + lo] = cp[n];
  }
  __syncthreads();

  if (tid < 128) {
    rowpart[(size_t)bn * BSZ + tileRow + tid] = rsum2[0][tid] + rsum2[1][tid];
    colpart[(size_t)bm * BSZ + tileCol + tid] = csum2[0][tid] + csum2[1][tid];
  }
}

// ---------- kernel 4: reduce partials + final expression ----------
__global__ void __launch_bounds__(256) k_final(const float* __restrict__ rowpart,
                                               const float* __restrict__ colpart,
                                               const float* __restrict__ dg,
                                               float* __restrict__ out) {
  const int k = blockIdx.x * 256 + threadIdx.x;
  float rs = 0.f, cs = 0.f;
#pragma unroll 8
  for (int s = 0; s < NTILE; ++s) {
    rs += rowpart[(size_t)s * BSZ + k];
    cs += colpart[(size_t)s * BSZ + k];
  }
  float d = dg[k];
  float p = __expf(d);
  out[k] = logf(cs - p) + logf(rs - p) - 2.0f * d;
}

extern "C" void kernel_launch(void* const* d_in, const int* in_sizes, int n_in,
                              void* d_out, int out_size, void* d_ws, size_t ws_size,
                              hipStream_t stream) {
  const float* X = (const float*)d_in[0];
  const float* Y = (const float*)d_in[1];
  float* out = (float*)d_out;

  char* ws = (char*)d_ws;
  // layout: Xn (32MB) | Yn (32MB) | diag (32KB) | rowpart (2MB) | colpart (2MB)
  unsigned short* Xn = (unsigned short*)ws;
  unsigned short* Yn = (unsigned short*)(ws + (size_t)BSZ * DIM * 2);
  float* diag = (float*)(ws + (size_t)BSZ * DIM * 4);
  float* rowpart = (float*)(ws + (size_t)BSZ * DIM * 4 + BSZ * 4);
  float* colpart = (float*)(ws + (size_t)BSZ * DIM * 4 + BSZ * 4 + (size_t)NTILE * BSZ * 4);

  k_norm<<<BSZ, 256, 0, stream>>>(X, Xn);
  k_norm<<<BSZ, 256, 0, stream>>>(Y, Yn);
  k_diag<<<BSZ, 256, 0, stream>>>(X, Y, diag);
  k_gemm<<<NTILE * NTILE, 256, 0, stream>>>(Xn, Yn, rowpart, colpart);
  k_final<<<BSZ / 256, 256, 0, stream>>>(rowpart, colpart, diag, out);
}

// Round 3
// 343.334 us; speedup vs baseline: 1.2682x; 1.0240x over previous
//
#include <hip/hip_runtime.h>
#include <hip/hip_bf16.h>
#include <math.h>

typedef float f32x4 __attribute__((ext_vector_type(4)));
typedef __bf16 bf16x8 __attribute__((ext_vector_type(8)));
typedef unsigned short ushort8 __attribute__((ext_vector_type(8)));

#define BSZ 8192
#define DIM 2048
#define BM 256            // tile size (square)
#define NTILE 32          // 8192 / 256
#define BK 32
#define KSTEPS 64         // 2048 / 32
#define BUF_ELEMS (2*BM*BK)   // A+B per buffer = 16384 ushorts = 32 KB
#define A_OFF 0
#define B_OFF (BM*BK)

// ---------- round-to-nearest-even fp32 -> bf16 ----------
__device__ __forceinline__ unsigned short f2bf(float f) {
  union { float f; unsigned int u; } c; c.f = f;
  unsigned int r = c.u + 0x7FFFu + ((c.u >> 16) & 1u);
  return (unsigned short)(r >> 16);
}

// ---------- kernel 1: fused normalize(X), normalize(Y), diag cos ----------
__global__ void __launch_bounds__(256) k_prep(const float* __restrict__ X,
                                              const float* __restrict__ Y,
                                              unsigned short* __restrict__ Xn,
                                              unsigned short* __restrict__ Yn,
                                              float* __restrict__ dg) {
  const int row = blockIdx.x;
  const int tid = threadIdx.x;
  const float4* xp = (const float4*)(X + (size_t)row * DIM);
  const float4* yp = (const float4*)(Y + (size_t)row * DIM);
  float4 x0 = xp[tid * 2], x1 = xp[tid * 2 + 1];
  float4 y0 = yp[tid * 2], y1 = yp[tid * 2 + 1];
  float sxx = x0.x*x0.x + x0.y*x0.y + x0.z*x0.z + x0.w*x0.w
            + x1.x*x1.x + x1.y*x1.y + x1.z*x1.z + x1.w*x1.w;
  float syy = y0.x*y0.x + y0.y*y0.y + y0.z*y0.z + y0.w*y0.w
            + y1.x*y1.x + y1.y*y1.y + y1.z*y1.z + y1.w*y1.w;
  float sxy = x0.x*y0.x + x0.y*y0.y + x0.z*y0.z + x0.w*y0.w
            + x1.x*y1.x + x1.y*y1.y + x1.z*y1.z + x1.w*y1.w;
#pragma unroll
  for (int m = 32; m >= 1; m >>= 1) {
    sxx += __shfl_xor(sxx, m);
    syy += __shfl_xor(syy, m);
    sxy += __shfl_xor(sxy, m);
  }
  __shared__ float sh[3][4];
  if ((tid & 63) == 0) {
    sh[0][tid >> 6] = sxx; sh[1][tid >> 6] = syy; sh[2][tid >> 6] = sxy;
  }
  __syncthreads();
  float xx = sh[0][0] + sh[0][1] + sh[0][2] + sh[0][3];
  float yy = sh[1][0] + sh[1][1] + sh[1][2] + sh[1][3];
  float xy = sh[2][0] + sh[2][1] + sh[2][2] + sh[2][3];
  float nx = fmaxf(sqrtf(xx), 1e-8f);
  float ny = fmaxf(sqrtf(yy), 1e-8f);
  float ix = 1.0f / nx, iy = 1.0f / ny;
  float vx[8] = {x0.x, x0.y, x0.z, x0.w, x1.x, x1.y, x1.z, x1.w};
  float vy[8] = {y0.x, y0.y, y0.z, y0.w, y1.x, y1.y, y1.z, y1.w};
  ushort8 ox, oy;
#pragma unroll
  for (int i = 0; i < 8; ++i) { ox[i] = f2bf(vx[i] * ix); oy[i] = f2bf(vy[i] * iy); }
  *(ushort8*)(Xn + (size_t)row * DIM + tid * 8) = ox;
  *(ushort8*)(Yn + (size_t)row * DIM + tid * 8) = oy;
  if (tid == 0) dg[row] = xy / (nx * ny);
}

// ---------- kernel 2: 256x256-tile bf16 MFMA GEMM, counted-vmcnt 4-buffer pipeline ----------
// LDS swizzle (64-B rows): physical 16B chunk p of row r holds logical chunk
// p ^ ((r>>1)&3). Applied inversely on the global_load_lds SOURCE address and
// forward on the ds_read side (rule #21). 16 frag rows -> 8 distinct bank
// slots = 2-way = free.
// Pipeline: iter t: issue stage of tile (t+2)&63 into buf[(t+2)&3] (4 loads),
// ds_read frags of tile t from buf[t&3], 32 MFMA, s_waitcnt vmcnt(4) (tile t+1
// landed; tile t+2 still in flight), raw s_barrier. Stage target was last read
// at iter t-2 (two barriers of margin). Never drains vmcnt to 0 in the loop.
__global__ void __launch_bounds__(512, 2) k_gemm(const unsigned short* __restrict__ Xn,
                                                 const unsigned short* __restrict__ Yn,
                                                 float* __restrict__ rowpart,
                                                 float* __restrict__ colpart) {
  // bijective XCD swizzle (nwg = 1024, divisible by 8)
  const int nwg = NTILE * NTILE;
  const int wgid = ((int)blockIdx.x & 7) * (nwg >> 3) + ((int)blockIdx.x >> 3);
  const int bm = wgid & (NTILE - 1);
  const int bn = wgid >> 5;
  const int tileRow = bm * BM;
  const int tileCol = bn * BM;

  __shared__ __align__(16) unsigned short lds[4 * BUF_ELEMS];  // 128 KiB
  __shared__ float rsum[4][BM];
  __shared__ float csum[2][BM];

  const int tid = threadIdx.x;
  const int lane = tid & 63;
  const int w = tid >> 6;            // wave 0..7
  const int wr = w >> 2;             // 0..1 : 128-row half
  const int wc = w & 3;              // 0..3 : 64-col quarter
  const int lo = lane & 15;
  const int hi = lane >> 4;

  f32x4 acc[8][4];
#pragma unroll
  for (int m = 0; m < 8; ++m)
#pragma unroll
    for (int n = 0; n < 4; ++n) acc[m][n] = (f32x4){0.f, 0.f, 0.f, 0.f};

  // staging source (per lane): lane l covers row l>>2 (of a 16-row group),
  // physical chunk l&3, whose logical (global) chunk is (l&3)^((l>>3)&3).
  const int srcrow = lane >> 2;
  const int srccol = ((lane & 3) ^ ((lane >> 3) & 3)) * 8;
  const unsigned short* gA = Xn + (size_t)(tileRow + w * 16 + srcrow) * DIM + srccol;
  const unsigned short* gB = Yn + (size_t)(tileCol + w * 16 + srcrow) * DIM + srccol;

#define STAGE(tt, bufi) do {                                                         \
    const int kb_ = (tt) * BK;                                                       \
    unsigned short* la_ = &lds[(bufi) * BUF_ELEMS + A_OFF + (w * 16) * BK];          \
    unsigned short* lb_ = &lds[(bufi) * BUF_ELEMS + B_OFF + (w * 16) * BK];          \
    __builtin_amdgcn_global_load_lds(                                                \
        (const __attribute__((address_space(1))) void*)(gA + kb_),                   \
        (__attribute__((address_space(3))) void*)la_, 16, 0, 0);                     \
    __builtin_amdgcn_global_load_lds(                                                \
        (const __attribute__((address_space(1))) void*)(gA + (size_t)128 * DIM + kb_), \
        (__attribute__((address_space(3))) void*)(la_ + 128 * BK), 16, 0, 0);        \
    __builtin_amdgcn_global_load_lds(                                                \
        (const __attribute__((address_space(1))) void*)(gB + kb_),                   \
        (__attribute__((address_space(3))) void*)lb_, 16, 0, 0);                     \
    __builtin_amdgcn_global_load_lds(                                                \
        (const __attribute__((address_space(1))) void*)(gB + (size_t)128 * DIM + kb_), \
        (__attribute__((address_space(3))) void*)(lb_ + 128 * BK), 16, 0, 0);        \
  } while (0)

  // prologue: tiles 0 and 1
  STAGE(0, 0);
  asm volatile("" ::: "memory");     // keep tile-0 issues oldest
  STAGE(1, 1);
  asm volatile("s_waitcnt vmcnt(4)" ::: "memory");   // tile 0 landed
  __builtin_amdgcn_s_barrier();
  __builtin_amdgcn_sched_barrier(0);

  const int rchunk = (hi ^ ((lo >> 1) & 3)) * 8;     // swizzled k-chunk (elements)

  for (int t = 0; t < KSTEPS; ++t) {
    STAGE((t + 2) & (KSTEPS - 1), (t + 2) & 3);

    const unsigned short* Abase = &lds[(t & 3) * BUF_ELEMS + A_OFF];
    const unsigned short* Bbase = &lds[(t & 3) * BUF_ELEMS + B_OFF];
    bf16x8 a[8], b[4];
#pragma unroll
    for (int m = 0; m < 8; ++m)
      a[m] = *(const bf16x8*)&Abase[(wr * 128 + m * 16 + lo) * BK + rchunk];
#pragma unroll
    for (int n = 0; n < 4; ++n)
      b[n] = *(const bf16x8*)&Bbase[(wc * 64 + n * 16 + lo) * BK + rchunk];

#pragma unroll
    for (int m = 0; m < 8; ++m)
#pragma unroll
      for (int n = 0; n < 4; ++n)
        acc[m][n] = __builtin_amdgcn_mfma_f32_16x16x32_bf16(a[m], b[n], acc[m][n], 0, 0, 0);

    asm volatile("s_waitcnt vmcnt(4)" ::: "memory");  // tile t+1 landed; t+2 in flight
    __builtin_amdgcn_s_barrier();
    __builtin_amdgcn_sched_barrier(0);
  }

  // ---- epilogue: exp + per-tile row/col sums ----
  // acc[m][n][q]: row = wr*128 + m*16 + hi*4 + q, col = wc*64 + n*16 + lo
  float rp[8][4];
  float cp[4];
#pragma unroll
  for (int m = 0; m < 8; ++m)
#pragma unroll
    for (int q = 0; q < 4; ++q) rp[m][q] = 0.f;
#pragma unroll
  for (int n = 0; n < 4; ++n) cp[n] = 0.f;

#pragma unroll
  for (int m = 0; m < 8; ++m)
#pragma unroll
    for (int n = 0; n < 4; ++n)
#pragma unroll
      for (int q = 0; q < 4; ++q) {
        float e = __expf(acc[m][n][q]);
        rp[m][q] += e;
        cp[n] += e;
      }

#pragma unroll
  for (int m = 0; m < 8; ++m)
#pragma unroll
    for (int q = 0; q < 4; ++q) {
      float v = rp[m][q];
      v += __shfl_xor(v, 1);
      v += __shfl_xor(v, 2);
      v += __shfl_xor(v, 4);
      v += __shfl_xor(v, 8);
      rp[m][q] = v;
    }
#pragma unroll
  for (int n = 0; n < 4; ++n) {
    float v = cp[n];
    v += __shfl_xor(v, 16);
    v += __shfl_xor(v, 32);
    cp[n] = v;
  }

  if (lo == 0) {
#pragma unroll
    for (int m = 0; m < 8; ++m)
#pragma unroll
      for (int q = 0; q < 4; ++q)
        rsum[wc][wr * 128 + m * 16 + hi * 4 + q] = rp[m][q];
  }
  if (hi == 0) {
#pragma unroll
    for (int n = 0; n < 4; ++n)
      csum[wr][wc * 64 + n * 16 + lo] = cp[n];
  }
  __syncthreads();

  if (tid < BM) {
    float r = rsum[0][tid] + rsum[1][tid] + rsum[2][tid] + rsum[3][tid];
    float c = csum[0][tid] + csum[1][tid];
    rowpart[(size_t)bn * BSZ + tileRow + tid] = r;
    colpart[(size_t)bm * BSZ + tileCol + tid] = c;
  }
#undef STAGE
}

// ---------- kernel 3: reduce partials + final expression ----------
__global__ void __launch_bounds__(256) k_final(const float* __restrict__ rowpart,
                                               const float* __restrict__ colpart,
                                               const float* __restrict__ dg,
                                               float* __restrict__ out) {
  const int k = blockIdx.x * 256 + threadIdx.x;
  float rs = 0.f, cs = 0.f;
#pragma unroll 8
  for (int s = 0; s < NTILE; ++s) {
    rs += rowpart[(size_t)s * BSZ + k];
    cs += colpart[(size_t)s * BSZ + k];
  }
  float d = dg[k];
  float p = __expf(d);
  out[k] = logf(cs - p) + logf(rs - p) - 2.0f * d;
}

extern "C" void kernel_launch(void* const* d_in, const int* in_sizes, int n_in,
                              void* d_out, int out_size, void* d_ws, size_t ws_size,
                              hipStream_t stream) {
  const float* X = (const float*)d_in[0];
  const float* Y = (const float*)d_in[1];
  float* out = (float*)d_out;

  char* ws = (char*)d_ws;
  // layout: Xn (32MB) | Yn (32MB) | diag (32KB) | rowpart (1MB) | colpart (1MB)
  unsigned short* Xn = (unsigned short*)ws;
  unsigned short* Yn = (unsigned short*)(ws + (size_t)BSZ * DIM * 2);
  float* diag = (float*)(ws + (size_t)BSZ * DIM * 4);
  float* rowpart = (float*)(ws + (size_t)BSZ * DIM * 4 + BSZ * 4);
  float* colpart = (float*)(ws + (size_t)BSZ * DIM * 4 + BSZ * 4 + (size_t)NTILE * BSZ * 4);

  k_prep<<<BSZ, 256, 0, stream>>>(X, Y, Xn, Yn, diag);
  k_gemm<<<NTILE * NTILE, 512, 0, stream>>>(Xn, Yn, rowpart, colpart);
  k_final<<<BSZ / 256, 256, 0, stream>>>(rowpart, colpart, diag, out);
}

// Round 4
// 191.128 us; speedup vs baseline: 2.2782x; 1.7964x over previous
//
#include <hip/hip_runtime.h>
#include <hip/hip_bf16.h>
#include <math.h>

typedef float f32x4 __attribute__((ext_vector_type(4)));
typedef int   i32x4 __attribute__((ext_vector_type(4)));
typedef int   i32x8 __attribute__((ext_vector_type(8)));

#define BSZ 8192
#define DIM 2048
#define NTILE 64          // 8192 / 128 tiles per side
#define BK 128            // K elements per step (one MX mfma)
#define KSTEPS 16         // 2048 / 128

// MX e8m0 scale byte for 2^-4 (we pre-scale inputs by 16): 127-4 = 123.
// All 4 bytes set so any opsel interpretation reads the same value.
#define SCALE_I32 0x7B7B7B7B

// ---------- kernel 1: fused normalize -> fp8(x*16), diag cos (fp32) ----------
__global__ void __launch_bounds__(256) k_prep(const float* __restrict__ X,
                                              const float* __restrict__ Y,
                                              unsigned char* __restrict__ Xq,
                                              unsigned char* __restrict__ Yq,
                                              float* __restrict__ dg) {
  const int row = blockIdx.x;
  const int tid = threadIdx.x;
  const float4* xp = (const float4*)(X + (size_t)row * DIM);
  const float4* yp = (const float4*)(Y + (size_t)row * DIM);
  float4 x0 = xp[tid * 2], x1 = xp[tid * 2 + 1];
  float4 y0 = yp[tid * 2], y1 = yp[tid * 2 + 1];
  float sxx = x0.x*x0.x + x0.y*x0.y + x0.z*x0.z + x0.w*x0.w
            + x1.x*x1.x + x1.y*x1.y + x1.z*x1.z + x1.w*x1.w;
  float syy = y0.x*y0.x + y0.y*y0.y + y0.z*y0.z + y0.w*y0.w
            + y1.x*y1.x + y1.y*y1.y + y1.z*y1.z + y1.w*y1.w;
  float sxy = x0.x*y0.x + x0.y*y0.y + x0.z*y0.z + x0.w*y0.w
            + x1.x*y1.x + x1.y*y1.y + x1.z*y1.z + x1.w*y1.w;
#pragma unroll
  for (int m = 32; m >= 1; m >>= 1) {
    sxx += __shfl_xor(sxx, m);
    syy += __shfl_xor(syy, m);
    sxy += __shfl_xor(sxy, m);
  }
  __shared__ float sh[3][4];
  if ((tid & 63) == 0) {
    sh[0][tid >> 6] = sxx; sh[1][tid >> 6] = syy; sh[2][tid >> 6] = sxy;
  }
  __syncthreads();
  float xx = sh[0][0] + sh[0][1] + sh[0][2] + sh[0][3];
  float yy = sh[1][0] + sh[1][1] + sh[1][2] + sh[1][3];
  float xy = sh[2][0] + sh[2][1] + sh[2][2] + sh[2][3];
  float nx = fmaxf(sqrtf(xx), 1e-8f);
  float ny = fmaxf(sqrtf(yy), 1e-8f);
  float ix = 16.0f / nx, iy = 16.0f / ny;   // x16 pre-scale into e4m3 sweet spot
  float vx[8] = {x0.x, x0.y, x0.z, x0.w, x1.x, x1.y, x1.z, x1.w};
  float vy[8] = {y0.x, y0.y, y0.z, y0.w, y1.x, y1.y, y1.z, y1.w};
  int px0 = __builtin_amdgcn_cvt_pk_fp8_f32(vx[0]*ix, vx[1]*ix, 0, false);
  px0     = __builtin_amdgcn_cvt_pk_fp8_f32(vx[2]*ix, vx[3]*ix, px0, true);
  int px1 = __builtin_amdgcn_cvt_pk_fp8_f32(vx[4]*ix, vx[5]*ix, 0, false);
  px1     = __builtin_amdgcn_cvt_pk_fp8_f32(vx[6]*ix, vx[7]*ix, px1, true);
  int py0 = __builtin_amdgcn_cvt_pk_fp8_f32(vy[0]*iy, vy[1]*iy, 0, false);
  py0     = __builtin_amdgcn_cvt_pk_fp8_f32(vy[2]*iy, vy[3]*iy, py0, true);
  int py1 = __builtin_amdgcn_cvt_pk_fp8_f32(vy[4]*iy, vy[5]*iy, 0, false);
  py1     = __builtin_amdgcn_cvt_pk_fp8_f32(vy[6]*iy, vy[7]*iy, py1, true);
  int2 ox; ox.x = px0; ox.y = px1;
  int2 oy; oy.x = py0; oy.y = py1;
  *(int2*)(Xq + (size_t)row * DIM + tid * 8) = ox;
  *(int2*)(Yq + (size_t)row * DIM + tid * 8) = oy;
  if (tid == 0) dg[row] = xy / (nx * ny);
}

// ---------- kernel 2: 128x128-tile MX-fp8 (K=128) MFMA GEMM ----------
// Round-2 verified structure (2-barrier per K-step, global_load_lds w=16,
// XOR-8 swizzle), dtype ported to fp8 e4m3 with block-scaled MX mfma.
// LDS rows are 128 B = 8 chunks of 16 B. physical chunk p of row r holds
// logical chunk p ^ (r&7); inverse applied on the global source (rule #21),
// forward XOR on the ds_read side.
__global__ void __launch_bounds__(256) k_gemm(const unsigned char* __restrict__ Xq,
                                              const unsigned char* __restrict__ Yq,
                                              float* __restrict__ rowpart,
                                              float* __restrict__ colpart) {
  const int bm = blockIdx.x & (NTILE - 1);
  const int bn = blockIdx.x >> 6;
  const int tileRow = bm * 128;
  const int tileCol = bn * 128;

  __shared__ __align__(16) unsigned char As[128][BK];   // 16 KiB
  __shared__ __align__(16) unsigned char Bs[128][BK];   // 16 KiB
  __shared__ float rsum2[2][128];
  __shared__ float csum2[2][128];

  const int tid = threadIdx.x;
  const int lane = tid & 63;
  const int w = tid >> 6;        // wave 0..3
  const int wr = w >> 1;         // wave row 0..1  (64-row sub-tile)
  const int wc = w & 1;          // wave col 0..1  (64-col sub-tile)
  const int lo = lane & 15;
  const int hi = lane >> 4;

  f32x4 acc[4][4];
#pragma unroll
  for (int m = 0; m < 4; ++m)
#pragma unroll
    for (int n = 0; n < 4; ++n) acc[m][n] = (f32x4){0.f, 0.f, 0.f, 0.f};

  // staging: wave w covers rows [w*32, w*32+32), 8 rows per issue, 4 issues.
  // lane l: row w*32 + i*8 + (l>>3), physical chunk l&7 -> logical (l&7)^(l>>3).
  const size_t lrow = (size_t)(lane >> 3);
  const int    lcol = (((lane & 7) ^ (lane >> 3)) * 16);
  const unsigned char* gxa = Xq + ((size_t)(tileRow + w * 32) + lrow) * DIM + lcol;
  const unsigned char* gyb = Yq + ((size_t)(tileCol + w * 32) + lrow) * DIM + lcol;

  for (int t = 0; t < KSTEPS; ++t) {
    const int kbase = t * BK;
#pragma unroll
    for (int i = 0; i < 4; ++i) {
      __builtin_amdgcn_global_load_lds(
          (const __attribute__((address_space(1))) void*)(gxa + (size_t)i * 8 * DIM + kbase),
          (__attribute__((address_space(3))) void*)&As[w * 32 + i * 8][0],
          16, 0, 0);
      __builtin_amdgcn_global_load_lds(
          (const __attribute__((address_space(1))) void*)(gyb + (size_t)i * 8 * DIM + kbase),
          (__attribute__((address_space(3))) void*)&Bs[w * 32 + i * 8][0],
          16, 0, 0);
    }
    __syncthreads();

    // fragment reads: lane holds 32 consecutive fp8 (k = hi*32 .. +31) of its
    // row -> logical chunks 2*hi, 2*hi+1; physical chunk = c ^ (row&7), row&7 = lo&7.
    union Frag { i32x4 q[2]; i32x8 v; };
    Frag a[4], b[4];
#pragma unroll
    for (int m = 0; m < 4; ++m) {
      const unsigned char* r = &As[wr * 64 + m * 16 + lo][0];
      a[m].q[0] = *(const i32x4*)(r + (((hi * 2    ) ^ (lo & 7)) * 16));
      a[m].q[1] = *(const i32x4*)(r + (((hi * 2 + 1) ^ (lo & 7)) * 16));
    }
#pragma unroll
    for (int n = 0; n < 4; ++n) {
      const unsigned char* r = &Bs[wc * 64 + n * 16 + lo][0];
      b[n].q[0] = *(const i32x4*)(r + (((hi * 2    ) ^ (lo & 7)) * 16));
      b[n].q[1] = *(const i32x4*)(r + (((hi * 2 + 1) ^ (lo & 7)) * 16));
    }

#pragma unroll
    for (int m = 0; m < 4; ++m)
#pragma unroll
      for (int n = 0; n < 4; ++n)
        acc[m][n] = __builtin_amdgcn_mfma_scale_f32_16x16x128_f8f6f4(
            a[m].v, b[n].v, acc[m][n],
            0, 0,                 // cbsz = fp8 e4m3 (A), blgp = fp8 e4m3 (B)
            0, SCALE_I32,         // scale_a opsel, scale_a (2^-4)
            0, SCALE_I32);        // scale_b opsel, scale_b (2^-4)
    __syncthreads();
  }

  // ---- epilogue: exp + per-tile row/col sums ----
  // D layout (16x16 shapes): row = m*16 + hi*4 + q, col = n*16 + lo
  float rp[4][4];
  float cp[4];
#pragma unroll
  for (int m = 0; m < 4; ++m)
#pragma unroll
    for (int q = 0; q < 4; ++q) rp[m][q] = 0.f;
#pragma unroll
  for (int n = 0; n < 4; ++n) cp[n] = 0.f;

#pragma unroll
  for (int m = 0; m < 4; ++m)
#pragma unroll
    for (int n = 0; n < 4; ++n)
#pragma unroll
      for (int q = 0; q < 4; ++q) {
        float e = __expf(acc[m][n][q]);
        rp[m][q] += e;
        cp[n] += e;
      }

#pragma unroll
  for (int m = 0; m < 4; ++m)
#pragma unroll
    for (int q = 0; q < 4; ++q) {
      float v = rp[m][q];
      v += __shfl_xor(v, 1);
      v += __shfl_xor(v, 2);
      v += __shfl_xor(v, 4);
      v += __shfl_xor(v, 8);
      rp[m][q] = v;
    }
#pragma unroll
  for (int n = 0; n < 4; ++n) {
    float v = cp[n];
    v += __shfl_xor(v, 16);
    v += __shfl_xor(v, 32);
    cp[n] = v;
  }

  if (lo == 0) {
#pragma unroll
    for (int m = 0; m < 4; ++m)
#pragma unroll
      for (int q = 0; q < 4; ++q)
        rsum2[wc][wr * 64 + m * 16 + hi * 4 + q] = rp[m][q];
  }
  if (hi == 0) {
#pragma unroll
    for (int n = 0; n < 4; ++n)
      csum2[wr][wc * 64 + n * 16 + lo] = cp[n];
  }
  __syncthreads();

  if (tid < 128) {
    rowpart[(size_t)bn * BSZ + tileRow + tid] = rsum2[0][tid] + rsum2[1][tid];
    colpart[(size_t)bm * BSZ + tileCol + tid] = csum2[0][tid] + csum2[1][tid];
  }
}

// ---------- kernel 3: reduce partials + final expression ----------
__global__ void __launch_bounds__(256) k_final(const float* __restrict__ rowpart,
                                               const float* __restrict__ colpart,
                                               const float* __restrict__ dg,
                                               float* __restrict__ out) {
  const int k = blockIdx.x * 256 + threadIdx.x;
  float rs = 0.f, cs = 0.f;
#pragma unroll 8
  for (int s = 0; s < NTILE; ++s) {
    rs += rowpart[(size_t)s * BSZ + k];
    cs += colpart[(size_t)s * BSZ + k];
  }
  float d = dg[k];
  float p = __expf(d);
  out[k] = logf(cs - p) + logf(rs - p) - 2.0f * d;
}

extern "C" void kernel_launch(void* const* d_in, const int* in_sizes, int n_in,
                              void* d_out, int out_size, void* d_ws, size_t ws_size,
                              hipStream_t stream) {
  const float* X = (const float*)d_in[0];
  const float* Y = (const float*)d_in[1];
  float* out = (float*)d_out;

  char* ws = (char*)d_ws;
  // layout: Xq (16MB) | Yq (16MB) | diag (32KB) | rowpart (2MB) | colpart (2MB)
  unsigned char* Xq = (unsigned char*)ws;
  unsigned char* Yq = (unsigned char*)(ws + (size_t)BSZ * DIM);
  float* diag = (float*)(ws + (size_t)BSZ * DIM * 2);
  float* rowpart = (float*)(ws + (size_t)BSZ * DIM * 2 + BSZ * 4);
  float* colpart = (float*)(ws + (size_t)BSZ * DIM * 2 + BSZ * 4 + (size_t)NTILE * BSZ * 4);

  k_prep<<<BSZ, 256, 0, stream>>>(X, Y, Xq, Yq, diag);
  k_gemm<<<NTILE * NTILE, 256, 0, stream>>>(Xq, Yq, rowpart, colpart);
  k_final<<<BSZ / 256, 256, 0, stream>>>(rowpart, colpart, diag, out);
}